// Round 1
// baseline (506.988 us; speedup 1.0000x reference)
//
#include <hip/hip_runtime.h>

namespace {

constexpr int NB = 4;
constexpr int ND = 128;
constexpr int NH = 192;
constexpr int NW = 192;
constexpr int HS = 2;        // output rows per wave strip
constexpr int CD = 8;        // output planes per block (d-chunk)
constexpr int ACT = NW / 4;  // 48 active lanes (4 w per lane)

__global__ __launch_bounds__(256, 2)
void edge_loss3d(const float* __restrict__ pred,
                 const float* __restrict__ targ,
                 float* __restrict__ out)
{
    const int lane = threadIdx.x & 63;
    const int wid  = threadIdx.x >> 6;
    const int d0   = blockIdx.x * CD;
    const int strip = blockIdx.y * 4 + wid;   // 0..95
    const int h0   = strip * HS;
    const int b    = blockIdx.z;
    const bool actv = lane < ACT;
    const int w0   = lane * 4;

    const long long bbase = (long long)b * ND * NH * NW;

    // rolling per-plane quantities: [tensor][slot][kind: 0=ss 1=ts 2=st][row][w]
    float q[2][3][3][HS][4];
    float acc = 0.f;

    #pragma unroll
    for (int dd = 0; dd < CD + 2; ++dd) {
        const int p  = d0 - 1 + dd;          // x-plane consumed this iter
        const int sp_ = dd % 3;              // slot for q(p)
        const bool pv = (p >= 0) && (p < ND);

        // zero this slot
        #pragma unroll
        for (int t = 0; t < 2; ++t)
          #pragma unroll
          for (int k = 0; k < 3; ++k)
            #pragma unroll
            for (int r = 0; r < HS; ++r)
              #pragma unroll
              for (int j = 0; j < 4; ++j)
                q[t][sp_][k][r][j] = 0.f;

        #pragma unroll
        for (int rr = 0; rr < HS + 2; ++rr) {
            const int h = h0 - 1 + rr;
            const bool hv = pv && (h >= 0) && (h < NH) && actv;
            const long long off = ((long long)p * NH + h) * NW + w0;
            #pragma unroll
            for (int t = 0; t < 2; ++t) {
                const float* __restrict__ src = t ? targ : pred;
                float4 x = make_float4(0.f, 0.f, 0.f, 0.f);
                if (hv) x = *reinterpret_cast<const float4*>(src + bbase + off);
                // w-halo via in-wave shuffles; W boundaries are zeros naturally
                float xl = __shfl_up(x.w, 1, 64);
                if (lane == 0) xl = 0.f;                 // w = -1 pad
                float xr = __shfl_down(x.x, 1, 64);      // lane 47 gets lane 48's 0
                // s = smooth_w * x, t = sobel_w * x  (4 outputs per lane)
                float sv[4], tv[4];
                sv[0] = fmaf(2.f, x.x, xl  + x.y) * 0.25f;
                sv[1] = fmaf(2.f, x.y, x.x + x.z) * 0.25f;
                sv[2] = fmaf(2.f, x.z, x.y + x.w) * 0.25f;
                sv[3] = fmaf(2.f, x.w, x.z + xr ) * 0.25f;
                tv[0] = x.y - xl;
                tv[1] = x.z - x.x;
                tv[2] = x.w - x.y;
                tv[3] = xr  - x.z;
                // accumulate into (ss, ts, st) of affected output rows
                #pragma unroll
                for (int o = 0; o < HS; ++o) {
                    const int dw = rr - o;               // 0..2 = valid weight idx
                    if (dw < 0 || dw > 2) continue;
                    const float wS = (dw == 1) ? 0.5f : 0.25f;
                    #pragma unroll
                    for (int j = 0; j < 4; ++j) {
                        q[t][sp_][0][o][j] = fmaf(wS, sv[j], q[t][sp_][0][o][j]);
                        if (dw == 0)      q[t][sp_][1][o][j] -= sv[j];
                        else if (dw == 2) q[t][sp_][1][o][j] += sv[j];
                        q[t][sp_][2][o][j] = fmaf(wS, tv[j], q[t][sp_][2][o][j]);
                    }
                }
            }
        }

        // emit output plane op = p-1 once q(op-1), q(op), q(op+1) are live
        if (dd >= 2) {
            const int sm = (dd - 2) % 3;
            const int sc = (dd - 1) % 3;
            const int sp = sp_;
            float part = 0.f;
            #pragma unroll
            for (int r = 0; r < HS; ++r)
              #pragma unroll
              for (int j = 0; j < 4; ++j) {
                float e[2];
                #pragma unroll
                for (int t = 0; t < 2; ++t) {
                    const float gx = fmaf(2.f, q[t][sc][2][r][j],
                                          q[t][sm][2][r][j] + q[t][sp][2][r][j]) * 0.25f;
                    const float gy = fmaf(2.f, q[t][sc][1][r][j],
                                          q[t][sm][1][r][j] + q[t][sp][1][r][j]) * 0.25f;
                    const float gz = q[t][sp][0][r][j] - q[t][sm][0][r][j];
                    e[t] = sqrtf(fmaf(gx, gx, fmaf(gy, gy, fmaf(gz, gz, 1e-8f))));
                }
                part += fabsf(e[0] - e[1]);
              }
            if (actv) acc += part;
        }
    }

    // wave reduce -> block reduce -> one atomic per block
    #pragma unroll
    for (int off = 32; off > 0; off >>= 1)
        acc += __shfl_down(acc, off, 64);
    __shared__ float wsum[4];
    if (lane == 0) wsum[wid] = acc;
    __syncthreads();
    if (threadIdx.x == 0) {
        const float invN = 1.f / (float)((long long)NB * ND * NH * NW);
        atomicAdd(out, (wsum[0] + wsum[1] + wsum[2] + wsum[3]) * invN);
    }
}

} // namespace

extern "C" void kernel_launch(void* const* d_in, const int* in_sizes, int n_in,
                              void* d_out, int out_size, void* d_ws, size_t ws_size,
                              hipStream_t stream) {
    const float* pred = (const float*)d_in[0];
    const float* targ = (const float*)d_in[1];
    float* out = (float*)d_out;
    (void)in_sizes; (void)n_in; (void)out_size; (void)d_ws; (void)ws_size;

    hipMemsetAsync(out, 0, sizeof(float), stream);

    dim3 grid(ND / CD, NH / (HS * 4), NB);   // (16, 24, 4) = 1536 blocks
    dim3 block(256);
    edge_loss3d<<<grid, block, 0, stream>>>(pred, targ, out);
}

// Round 2
// 220.742 us; speedup vs baseline: 2.2967x; 2.2967x over previous
//
#include <hip/hip_runtime.h>

namespace {

constexpr int NB = 4;
constexpr int ND = 128;
constexpr int NH = 192;
constexpr int NW = 192;
constexpr int CD = 8;   // output planes per block

__global__ __launch_bounds__(256, 2)
void edge_loss3d(const float* __restrict__ pred,
                 const float* __restrict__ targ,
                 float* __restrict__ out)
{
    const int lane = threadIdx.x & 63;
    const int wid  = threadIdx.x >> 6;
    const int d0   = blockIdx.x * CD;
    const int h    = blockIdx.y * 4 + wid;   // this wave's output row, 0..191
    const int b    = blockIdx.z;
    const int w0   = lane * 3;               // 64 lanes x 3 w = 192, all active

    const long long base = (long long)b * ND * NH * NW;

    // rolling state: q[tensor][slot][kind 0=ss 1=ts 2=st][w]  (54 floats)
    float q[2][3][3][3];
    float acc = 0.f;

    #pragma unroll
    for (int dd = 0; dd < CD + 2; ++dd) {
        const int p  = d0 - 1 + dd;          // input plane consumed this iter
        const int sp = dd % 3;               // compile-time after unroll
        const bool pv = (p >= 0) && (p < ND);

        #pragma unroll
        for (int t = 0; t < 2; ++t) {
            const float* __restrict__ src = t ? targ : pred;
            #pragma unroll
            for (int rr = 0; rr < 3; ++rr) {
                const int hh = h - 1 + rr;
                const bool hv = pv && (hh >= 0) && (hh < NH);
                float x0 = 0.f, x1 = 0.f, x2 = 0.f;
                if (hv) {
                    const float* rp = src + base + ((long long)p * NH + hh) * NW + w0;
                    x0 = rp[0]; x1 = rp[1]; x2 = rp[2];
                }
                // w-halo via in-wave shuffles; boundary pads zeroed explicitly
                float xl = __shfl_up(x2, 1, 64);
                if (lane == 0)  xl = 0.f;    // w = -1 pad
                float xr = __shfl_down(x0, 1, 64);
                if (lane == 63) xr = 0.f;    // w = 192 pad
                // w-direction smooth (sv) and sobel (tv)
                float sv[3], tv[3];
                sv[0] = fmaf(2.f, x0, xl + x1) * 0.25f;
                sv[1] = fmaf(2.f, x1, x0 + x2) * 0.25f;
                sv[2] = fmaf(2.f, x2, x1 + xr) * 0.25f;
                tv[0] = x1 - xl;
                tv[1] = x2 - x0;
                tv[2] = xr - x1;
                // h-direction combine into (ss, ts, st); rr=0 assigns (no zero-init)
                #pragma unroll
                for (int j = 0; j < 3; ++j) {
                    if (rr == 0) {
                        q[t][sp][0][j] = 0.25f * sv[j];
                        q[t][sp][1][j] = -sv[j];
                        q[t][sp][2][j] = 0.25f * tv[j];
                    } else if (rr == 1) {
                        q[t][sp][0][j] = fmaf(0.5f, sv[j], q[t][sp][0][j]);
                        // sobel_h weight at center is 0 -> ts unchanged
                        q[t][sp][2][j] = fmaf(0.5f, tv[j], q[t][sp][2][j]);
                    } else {
                        q[t][sp][0][j] = fmaf(0.25f, sv[j], q[t][sp][0][j]);
                        q[t][sp][1][j] += sv[j];
                        q[t][sp][2][j] = fmaf(0.25f, tv[j], q[t][sp][2][j]);
                    }
                }
            }
        }

        // emit output plane op = p-1 once q(op-1), q(op), q(op+1) are live
        if (dd >= 2) {
            const int sm = (dd - 2) % 3;
            const int sc = (dd - 1) % 3;
            #pragma unroll
            for (int j = 0; j < 3; ++j) {
                float e[2];
                #pragma unroll
                for (int t = 0; t < 2; ++t) {
                    const float gx = fmaf(2.f, q[t][sc][2][j],
                                          q[t][sm][2][j] + q[t][sp][2][j]) * 0.25f;
                    const float gy = fmaf(2.f, q[t][sc][1][j],
                                          q[t][sm][1][j] + q[t][sp][1][j]) * 0.25f;
                    const float gz = q[t][sp][0][j] - q[t][sm][0][j];
                    e[t] = sqrtf(fmaf(gx, gx, fmaf(gy, gy, fmaf(gz, gz, 1e-8f))));
                }
                acc += fabsf(e[0] - e[1]);
            }
        }
    }

    // wave reduce -> block reduce -> one atomic per block
    #pragma unroll
    for (int off = 32; off > 0; off >>= 1)
        acc += __shfl_down(acc, off, 64);
    __shared__ float wsum[4];
    if (lane == 0) wsum[wid] = acc;
    __syncthreads();
    if (threadIdx.x == 0) {
        const float invN = 1.f / (float)((long long)NB * ND * NH * NW);
        atomicAdd(out, (wsum[0] + wsum[1] + wsum[2] + wsum[3]) * invN);
    }
}

} // namespace

extern "C" void kernel_launch(void* const* d_in, const int* in_sizes, int n_in,
                              void* d_out, int out_size, void* d_ws, size_t ws_size,
                              hipStream_t stream) {
    const float* pred = (const float*)d_in[0];
    const float* targ = (const float*)d_in[1];
    float* out = (float*)d_out;
    (void)in_sizes; (void)n_in; (void)out_size; (void)d_ws; (void)ws_size;

    hipMemsetAsync(out, 0, sizeof(float), stream);

    dim3 grid(ND / CD, NH / 4, NB);   // (16, 48, 4) = 3072 blocks, 4 waves each
    dim3 block(256);
    edge_loss3d<<<grid, block, 0, stream>>>(pred, targ, out);
}

// Round 3
// 103.208 us; speedup vs baseline: 4.9123x; 2.1388x over previous
//
#include <hip/hip_runtime.h>

namespace {

constexpr int NB = 4;
constexpr int ND = 128;
constexpr int NH = 192;
constexpr int NW = 192;
constexpr int CD = 9;   // output planes per block (3 steady-state groups of 3)

__global__ __launch_bounds__(256, 2)
void edge_loss3d(const float* __restrict__ pred,
                 const float* __restrict__ targ,
                 float* __restrict__ out)
{
    const int lane = threadIdx.x & 63;
    const int wid  = threadIdx.x >> 6;
    const int d0   = blockIdx.x * CD;
    const int h    = blockIdx.y * 4 + wid;   // this wave's output row, 0..191
    const int b    = blockIdx.z;
    const int w0   = lane * 3;               // 64 lanes x 3 w = 192, all active

    const long long base = (long long)b * ND * NH * NW;

    // rolling state: q[tensor][slot][kind 0=ss 1=ts 2=st][w]
    // EVERY index below is a textual literal -> guaranteed SROA to VGPRs.
    float q[2][3][3][3];
    float acc = 0.f;

// one h-row pass of one tensor into slot SP (T, SP, RR are literals)
#define ROWPASS(T, SP, RR, P) do {                                            \
    const float* __restrict__ src_ = (T) ? targ : pred;                       \
    const int hh_ = h - 1 + (RR);                                             \
    const bool hv_ = ((P) >= 0) && ((P) < ND) && (hh_ >= 0) && (hh_ < NH);    \
    float x0_ = 0.f, x1_ = 0.f, x2_ = 0.f;                                    \
    if (hv_) {                                                                \
        const float* rp_ = src_ + base + ((long long)(P) * NH + hh_) * NW + w0;\
        x0_ = rp_[0]; x1_ = rp_[1]; x2_ = rp_[2];                             \
    }                                                                         \
    float xl_ = __shfl_up(x2_, 1, 64);   if (lane == 0)  xl_ = 0.f;           \
    float xr_ = __shfl_down(x0_, 1, 64); if (lane == 63) xr_ = 0.f;           \
    const float s0_ = fmaf(2.f, x0_, xl_ + x1_) * 0.25f;                      \
    const float s1_ = fmaf(2.f, x1_, x0_ + x2_) * 0.25f;                      \
    const float s2_ = fmaf(2.f, x2_, x1_ + xr_) * 0.25f;                      \
    const float t0_ = x1_ - xl_, t1_ = x2_ - x0_, t2_ = xr_ - x1_;            \
    if ((RR) == 0) {                                                          \
        q[T][SP][0][0] = 0.25f*s0_; q[T][SP][0][1] = 0.25f*s1_; q[T][SP][0][2] = 0.25f*s2_; \
        q[T][SP][1][0] = -s0_;      q[T][SP][1][1] = -s1_;      q[T][SP][1][2] = -s2_;      \
        q[T][SP][2][0] = 0.25f*t0_; q[T][SP][2][1] = 0.25f*t1_; q[T][SP][2][2] = 0.25f*t2_; \
    } else if ((RR) == 1) {                                                   \
        q[T][SP][0][0] = fmaf(0.5f, s0_, q[T][SP][0][0]);                     \
        q[T][SP][0][1] = fmaf(0.5f, s1_, q[T][SP][0][1]);                     \
        q[T][SP][0][2] = fmaf(0.5f, s2_, q[T][SP][0][2]);                     \
        /* sobel_h center weight = 0 -> ts unchanged */                       \
        q[T][SP][2][0] = fmaf(0.5f, t0_, q[T][SP][2][0]);                     \
        q[T][SP][2][1] = fmaf(0.5f, t1_, q[T][SP][2][1]);                     \
        q[T][SP][2][2] = fmaf(0.5f, t2_, q[T][SP][2][2]);                     \
    } else {                                                                  \
        q[T][SP][0][0] = fmaf(0.25f, s0_, q[T][SP][0][0]);                    \
        q[T][SP][0][1] = fmaf(0.25f, s1_, q[T][SP][0][1]);                    \
        q[T][SP][0][2] = fmaf(0.25f, s2_, q[T][SP][0][2]);                    \
        q[T][SP][1][0] += s0_; q[T][SP][1][1] += s1_; q[T][SP][1][2] += s2_;  \
        q[T][SP][2][0] = fmaf(0.25f, t0_, q[T][SP][2][0]);                    \
        q[T][SP][2][1] = fmaf(0.25f, t1_, q[T][SP][2][1]);                    \
        q[T][SP][2][2] = fmaf(0.25f, t2_, q[T][SP][2][2]);                    \
    }                                                                         \
} while (0)

#define PROCESS(SP, P) do {                                                   \
    ROWPASS(0, SP, 0, P); ROWPASS(0, SP, 1, P); ROWPASS(0, SP, 2, P);         \
    ROWPASS(1, SP, 0, P); ROWPASS(1, SP, 1, P); ROWPASS(1, SP, 2, P);         \
} while (0)

#define EDGE(T, J, SM, SC, SP, EVAR) do {                                     \
    const float gx_ = fmaf(2.f, q[T][SC][2][J], q[T][SM][2][J] + q[T][SP][2][J]) * 0.25f; \
    const float gy_ = fmaf(2.f, q[T][SC][1][J], q[T][SM][1][J] + q[T][SP][1][J]) * 0.25f; \
    const float gz_ = q[T][SP][0][J] - q[T][SM][0][J];                        \
    EVAR = sqrtf(fmaf(gx_, gx_, fmaf(gy_, gy_, fmaf(gz_, gz_, 1e-8f))));      \
} while (0)

#define EMIT(SM, SC, SP, OP) do {                                             \
    if ((OP) < ND) {                                                          \
        float e0_, e1_;                                                       \
        EDGE(0, 0, SM, SC, SP, e0_); EDGE(1, 0, SM, SC, SP, e1_); acc += fabsf(e0_ - e1_); \
        EDGE(0, 1, SM, SC, SP, e0_); EDGE(1, 1, SM, SC, SP, e1_); acc += fabsf(e0_ - e1_); \
        EDGE(0, 2, SM, SC, SP, e0_); EDGE(1, 2, SM, SC, SP, e1_); acc += fabsf(e0_ - e1_); \
    }                                                                         \
} while (0)

    // prologue: planes d0-1 (slot 0), d0 (slot 1)
    PROCESS(0, d0 - 1);
    PROCESS(1, d0);

    // steady state: 3 groups x 3 phases; slot pattern (2,0,1) repeats
    for (int g = 0; g < 3; ++g) {
        const int p = d0 + 1 + g * 3;
        PROCESS(2, p);     EMIT(0, 1, 2, p - 1);
        PROCESS(0, p + 1); EMIT(1, 2, 0, p);
        PROCESS(1, p + 2); EMIT(2, 0, 1, p + 1);
    }

#undef ROWPASS
#undef PROCESS
#undef EDGE
#undef EMIT

    // wave reduce -> block reduce -> one atomic per block
    #pragma unroll
    for (int off = 32; off > 0; off >>= 1)
        acc += __shfl_down(acc, off, 64);
    __shared__ float wsum[4];
    if (lane == 0) wsum[wid] = acc;
    __syncthreads();
    if (threadIdx.x == 0) {
        const float invN = 1.f / (float)((long long)NB * ND * NH * NW);
        atomicAdd(out, (wsum[0] + wsum[1] + wsum[2] + wsum[3]) * invN);
    }
}

} // namespace

extern "C" void kernel_launch(void* const* d_in, const int* in_sizes, int n_in,
                              void* d_out, int out_size, void* d_ws, size_t ws_size,
                              hipStream_t stream) {
    const float* pred = (const float*)d_in[0];
    const float* targ = (const float*)d_in[1];
    float* out = (float*)d_out;
    (void)in_sizes; (void)n_in; (void)out_size; (void)d_ws; (void)ws_size;

    hipMemsetAsync(out, 0, sizeof(float), stream);

    dim3 grid((ND + CD - 1) / CD, NH / 4, NB);   // (15, 48, 4) = 2880 blocks
    dim3 block(256);
    edge_loss3d<<<grid, block, 0, stream>>>(pred, targ, out);
}